// Round 7
// baseline (636.930 us; speedup 1.0000x reference)
//
#include <hip/hip_runtime.h>

#define LRELU(x) ((x) > 0.f ? (x) : 0.01f * (x))

constexpr int C = 32;
constexpr int BSH = 8;            // 256 dst-nodes per bucket
constexpr int MAXBK = 512;        // max buckets (N <= 131072)

typedef int   iv4 __attribute__((ext_vector_type(4)));
typedef float fv4 __attribute__((ext_vector_type(4)));
typedef unsigned uv4 __attribute__((ext_vector_type(4)));

// ---- bf16 pack/unpack helpers ----
__device__ __forceinline__ unsigned pk_bf16(float a, float b) {
    unsigned ua = __float_as_uint(a), ub = __float_as_uint(b);
    unsigned ra = (ua + 0x7fffu + ((ua >> 16) & 1u)) >> 16;
    unsigned rb = (ub + 0x7fffu + ((ub >> 16) & 1u)) & 0xffff0000u;
    return ra | rb;
}
__device__ __forceinline__ float lo_bf16(unsigned w) { return __uint_as_float(w << 16); }
__device__ __forceinline__ float hi_bf16(unsigned w) { return __uint_as_float(w & 0xffff0000u); }

// ---- bucket histogram (LDS-privatized) ----
__global__ void k_bhist(const int* __restrict__ col, int* __restrict__ ghist, int E) {
    __shared__ int lh[MAXBK];
    for (int i = threadIdx.x; i < MAXBK; i += blockDim.x) lh[i] = 0;
    __syncthreads();
    int chunk = (E + gridDim.x - 1) / gridDim.x;
    int c0 = blockIdx.x * chunk, c1 = min(E, c0 + chunk);
    for (int e = c0 + threadIdx.x; e < c1; e += blockDim.x)
        atomicAdd(&lh[col[e] >> BSH], 1);
    __syncthreads();
    for (int i = threadIdx.x; i < MAXBK; i += blockDim.x) {
        int v = lh[i];
        if (v) atomicAdd(&ghist[i], v);
    }
}

// ---- exclusive scan of bucket counts -> bbase, gcur ----
__global__ void k_bscan(const int* __restrict__ ghist, int* __restrict__ bbase,
                        int* __restrict__ gcur, int nbk, int E) {
    __shared__ int sm[MAXBK];
    int tid = threadIdx.x;
    int v = (tid < nbk) ? ghist[tid] : 0;
    sm[tid] = v;
    __syncthreads();
    for (int off = 1; off < MAXBK; off <<= 1) {
        int t = (tid >= off) ? sm[tid - off] : 0;
        __syncthreads();
        sm[tid] += t;
        __syncthreads();
    }
    if (tid < nbk) {
        int excl = sm[tid] - v;
        bbase[tid] = excl;
        gcur[tid] = excl;
    }
    if (tid == 0) bbase[nbk] = E;
}

// ---- partition edges into buckets; per-wg claimed contiguous runs ----
// tmp entry: { src | (dstLow8 << 17), ea_bits }
__global__ void k_part(const int* __restrict__ row, const int* __restrict__ col,
                       const float* __restrict__ ea, int* __restrict__ gcur,
                       int2* __restrict__ tmp, int E) {
    __shared__ int lcnt[MAXBK];
    __shared__ int lbase[MAXBK];
    __shared__ int lcur[MAXBK];
    for (int i = threadIdx.x; i < MAXBK; i += blockDim.x) { lcnt[i] = 0; lcur[i] = 0; }
    __syncthreads();
    int chunk = (E + gridDim.x - 1) / gridDim.x;
    int c0 = blockIdx.x * chunk, c1 = min(E, c0 + chunk);
    for (int e = c0 + threadIdx.x; e < c1; e += blockDim.x)
        atomicAdd(&lcnt[col[e] >> BSH], 1);
    __syncthreads();
    for (int b = threadIdx.x; b < MAXBK; b += blockDim.x) {
        int c = lcnt[b];
        lbase[b] = c ? atomicAdd(&gcur[b], c) : 0;
    }
    __syncthreads();
    for (int e = c0 + threadIdx.x; e < c1; e += blockDim.x) {
        int cc = col[e];
        int b = cc >> BSH;
        int r = atomicAdd(&lcur[b], 1);
        tmp[lbase[b] + r] = make_int2(row[e] | ((cc & 255) << 17), __float_as_int(ea[e]));
    }
}

// ---- per-bucket CSR build ----
__global__ void k_build(const int* __restrict__ bbase, const int2* __restrict__ tmp,
                        int* __restrict__ rowptr, float* __restrict__ dinv,
                        int2* __restrict__ pairs, int N, int E) {
    __shared__ int ncnt[256], noff[256], ncur[256], scn[256];
    __shared__ float ndeg[256];
    int tid = threadIdx.x;
    int bg = blockIdx.x;
    int node0 = bg << BSH;
    int s = bbase[bg], e = bbase[bg + 1];
    ncnt[tid] = 0; ncur[tid] = 0; ndeg[tid] = 0.f;
    __syncthreads();
    for (int p = s + tid; p < e; p += 256) {
        int2 u = tmp[p];
        int nl = (u.x >> 17) & 255;
        atomicAdd(&ncnt[nl], 1);
        atomicAdd(&ndeg[nl], __int_as_float(u.y));
    }
    __syncthreads();
    int v = ncnt[tid];
    scn[tid] = v;
    __syncthreads();
    for (int off = 1; off < 256; off <<= 1) {
        int t = (tid >= off) ? scn[tid - off] : 0;
        __syncthreads();
        scn[tid] += t;
        __syncthreads();
    }
    {
        int excl = scn[tid] - v;
        noff[tid] = excl;
        int node = node0 + tid;
        if (node < N) {
            rowptr[node] = s + excl;
            float d = ndeg[tid];
            dinv[node] = d > 0.f ? rsqrtf(fmaxf(d, 1e-12f)) : 0.f;
        }
    }
    if (bg == gridDim.x - 1 && tid == 0) rowptr[N] = E;
    __syncthreads();
    for (int p = s + tid; p < e; p += 256) {
        int2 u = tmp[p];
        int nl = (u.x >> 17) & 255;
        int r = atomicAdd(&ncur[nl], 1);
        pairs[s + noff[nl] + r] = make_int2(u.x & 0x1FFFF, u.y);
    }
}

// ---- read-in MLP: h = lrelu([state,action]@W_in+b_in); v = bf16(dinv*h) ----
__global__ void k_inmlp(const float* __restrict__ state, const float* __restrict__ action,
                        const float* __restrict__ Win, const float* __restrict__ bin,
                        const float* __restrict__ dinv,
                        float* __restrict__ h, unsigned* __restrict__ v, int N) {
    int t = blockIdx.x * blockDim.x + threadIdx.x;
    int i = t >> 5, c = t & 31;
    if (i >= N) return;
    float acc = bin[c];
#pragma unroll
    for (int d = 0; d < 8; ++d) acc += state[i * 8 + d] * Win[d * 32 + c];
#pragma unroll
    for (int d = 0; d < 2; ++d) acc += action[i * 2 + d] * Win[(8 + d) * 32 + c];
    float hv = LRELU(acc);
    h[i * 32 + c] = hv;
    float vv = dinv[i] * hv;
    float other = __shfl_xor(vv, 1, 32);
    if ((c & 1) == 0) v[(size_t)i * 16 + (c >> 1)] = pk_bf16(vv, other);
}

// acc[8] (cols 8q..8q+7) += z(32-row, spread over 4 lanes as 8 floats) @ W
__device__ __forceinline__ void mm_acc8(float acc[8], const float z8[8],
                                        const float* __restrict__ W, int q) {
#pragma unroll
    for (int a = 0; a < 4; ++a) {
        float zr[8];
#pragma unroll
        for (int j = 0; j < 8; ++j) zr[j] = __shfl(z8[j], a, 4);
#pragma unroll
        for (int r = 0; r < 8; ++r) {
            const float* wrow = &W[(8 * a + r) * 32 + 8 * q];
            const float4 w0 = *(const float4*)wrow;
            const float4 w1 = *(const float4*)(wrow + 4);
            acc[0] += zr[r] * w0.x; acc[1] += zr[r] * w0.y;
            acc[2] += zr[r] * w0.z; acc[3] += zr[r] * w0.w;
            acc[4] += zr[r] * w1.x; acc[5] += zr[r] * w1.y;
            acc[6] += zr[r] * w1.z; acc[7] += zr[r] * w1.w;
        }
    }
}

__device__ __forceinline__ void edge_acc8(float tv[8], float w, uv4 x) {
    tv[0] += w * lo_bf16(x[0]); tv[1] += w * hi_bf16(x[0]);
    tv[2] += w * lo_bf16(x[1]); tv[3] += w * hi_bf16(x[1]);
    tv[4] += w * lo_bf16(x[2]); tv[5] += w * hi_bf16(x[2]);
    tv[6] += w * lo_bf16(x[3]); tv[7] += w * hi_bf16(x[3]);
}

// ---- fused tap; 4 lanes per node (uint4 = 16B of 64B bf16 row); nt streams ----
__global__ void k_tap4(const int* __restrict__ rowptr, const int2* __restrict__ pairs,
                       const uv4* __restrict__ vin, const float* __restrict__ hin,
                       const float* __restrict__ dinv,
                       float* __restrict__ outacc, uv4* __restrict__ vout,
                       float* __restrict__ hout, float* __restrict__ yout,
                       const float* __restrict__ Wl, int k, const float* __restrict__ bias,
                       const float* __restrict__ Wout, const float* __restrict__ bout,
                       int N, int first, int last, int readout) {
    int t = blockIdx.x * blockDim.x + threadIdx.x;
    int g = t >> 2, q = t & 3;
    if (g >= N) return;
    int s = rowptr[g], e = rowptr[g + 1];
    float tv[8] = {0.f, 0.f, 0.f, 0.f, 0.f, 0.f, 0.f, 0.f};
    int p = s;
    if ((p & 1) && p < e) {                 // peel to 16B-aligned pair index
        int2 pr = pairs[p];
        uv4 x = vin[((size_t)(unsigned)pr.x << 2) + q];
        edge_acc8(tv, __int_as_float(pr.y), x);
        ++p;
    }
#pragma unroll 2
    for (; p + 4 <= e; p += 4) {            // 4 edges: 2 nt pair-loads, 4 uv4 gathers
        iv4 pa = __builtin_nontemporal_load((const iv4*)&pairs[p]);
        iv4 pb = __builtin_nontemporal_load((const iv4*)&pairs[p + 2]);
        uv4 x0 = vin[((size_t)(unsigned)pa[0] << 2) + q];
        uv4 x1 = vin[((size_t)(unsigned)pa[2] << 2) + q];
        uv4 x2 = vin[((size_t)(unsigned)pb[0] << 2) + q];
        uv4 x3 = vin[((size_t)(unsigned)pb[2] << 2) + q];
        edge_acc8(tv, __int_as_float(pa[1]), x0);
        edge_acc8(tv, __int_as_float(pa[3]), x1);
        edge_acc8(tv, __int_as_float(pb[1]), x2);
        edge_acc8(tv, __int_as_float(pb[3]), x3);
    }
    for (; p < e; ++p) {                    // tail
        int2 pr = pairs[p];
        uv4 x = vin[((size_t)(unsigned)pr.x << 2) + q];
        edge_acc8(tv, __int_as_float(pr.y), x);
    }
    float di = dinv[g];
    float z8[8];
#pragma unroll
    for (int j = 0; j < 8; ++j) z8[j] = di * tv[j];
    const float* Wk = Wl + (size_t)k * 1024;
    float acc[8];
    if (first) {
#pragma unroll
        for (int j = 0; j < 8; ++j) acc[j] = bias[8 * q + j];
        fv4 ha = __builtin_nontemporal_load((const fv4*)&hin[(size_t)g * 32 + 8 * q]);
        fv4 hb = __builtin_nontemporal_load((const fv4*)&hin[(size_t)g * 32 + 8 * q + 4]);
        float h8[8] = {ha[0], ha[1], ha[2], ha[3], hb[0], hb[1], hb[2], hb[3]};
        mm_acc8(acc, h8, Wl, q);
    } else {
        fv4 oa = __builtin_nontemporal_load((const fv4*)&outacc[(size_t)g * 32 + 8 * q]);
        fv4 ob = __builtin_nontemporal_load((const fv4*)&outacc[(size_t)g * 32 + 8 * q + 4]);
        acc[0] = oa[0]; acc[1] = oa[1]; acc[2] = oa[2]; acc[3] = oa[3];
        acc[4] = ob[0]; acc[5] = ob[1]; acc[6] = ob[2]; acc[7] = ob[3];
    }
    mm_acc8(acc, z8, Wk, q);
    if (!last) {
        fv4 oa = {acc[0], acc[1], acc[2], acc[3]};
        fv4 ob = {acc[4], acc[5], acc[6], acc[7]};
        __builtin_nontemporal_store(oa, (fv4*)&outacc[(size_t)g * 32 + 8 * q]);
        __builtin_nontemporal_store(ob, (fv4*)&outacc[(size_t)g * 32 + 8 * q + 4]);
        uv4 vo = {pk_bf16(di * z8[0], di * z8[1]), pk_bf16(di * z8[2], di * z8[3]),
                  pk_bf16(di * z8[4], di * z8[5]), pk_bf16(di * z8[6], di * z8[7])};
        vout[((size_t)g << 2) + q] = vo;
    } else {
        float hv[8];
#pragma unroll
        for (int j = 0; j < 8; ++j) hv[j] = LRELU(acc[j]);
        if (!readout) {
            float4 h0 = {hv[0], hv[1], hv[2], hv[3]};
            float4 h1 = {hv[4], hv[5], hv[6], hv[7]};
            *(float4*)&hout[(size_t)g * 32 + 8 * q] = h0;
            *(float4*)&hout[(size_t)g * 32 + 8 * q + 4] = h1;
            uv4 vo = {pk_bf16(di * hv[0], di * hv[1]), pk_bf16(di * hv[2], di * hv[3]),
                      pk_bf16(di * hv[4], di * hv[5]), pk_bf16(di * hv[6], di * hv[7])};
            vout[((size_t)g << 2) + q] = vo;
        } else {
            float v = 0.f;
#pragma unroll
            for (int j = 0; j < 8; ++j) v += hv[j] * Wout[8 * q + j];
            v += __shfl_xor(v, 2, 4);
            v += __shfl_xor(v, 1, 4);
            if (q == 0) yout[g] = v + bout[0];
        }
    }
}

// ---- segmented mean over sorted batch: one block per graph ----
__global__ void k_segmean(const float* __restrict__ y, const int* __restrict__ batch,
                          float* __restrict__ out, int N) {
    int b = blockIdx.x;
    __shared__ int slo, shi;
    if (threadIdx.x == 0) {
        int lo = 0, hi = N;
        while (lo < hi) { int m = (lo + hi) >> 1; if (batch[m] < b) lo = m + 1; else hi = m; }
        slo = lo;
        hi = N;
        while (lo < hi) { int m = (lo + hi) >> 1; if (batch[m] < b + 1) lo = m + 1; else hi = m; }
        shi = lo;
    }
    __syncthreads();
    int lo = slo, hi = shi;
    float sum = 0.f;
    for (int i = lo + threadIdx.x; i < hi; i += blockDim.x) sum += y[i];
    __shared__ float sm[256];
    sm[threadIdx.x] = sum;
    __syncthreads();
    for (int o = 128; o; o >>= 1) {
        if (threadIdx.x < o) sm[threadIdx.x] += sm[threadIdx.x + o];
        __syncthreads();
    }
    if (threadIdx.x == 0) out[b] = sm[0] / fmaxf((float)(hi - lo), 1.0f);
}

static inline size_t algn(size_t x) { return (x + 255) & ~(size_t)255; }

extern "C" void kernel_launch(void* const* d_in, const int* in_sizes, int n_in,
                              void* d_out, int out_size, void* d_ws, size_t ws_size,
                              hipStream_t stream) {
    const float* state  = (const float*)d_in[0];
    const float* action = (const float*)d_in[1];
    const int*   eidx   = (const int*)d_in[2];
    const float* eattr  = (const float*)d_in[3];
    const int*   batch  = (const int*)d_in[4];
    const float* Win    = (const float*)d_in[5];
    const float* bin    = (const float*)d_in[6];
    const float* Wtaps  = (const float*)d_in[7];
    const float* bgnn   = (const float*)d_in[8];
    const float* Wout   = (const float*)d_in[9];
    const float* bout   = (const float*)d_in[10];
    float* out = (float*)d_out;

    const int N = in_sizes[0] / 8;       // SD=8
    const int E = in_sizes[3];
    const int B = out_size;
    const int K = 4, L = 2;
    const int NBK = (N + 255) >> BSH;

    const int* row = eidx;
    const int* col = eidx + E;

    // ---- workspace layout ----
    char* base = (char*)d_ws;
    int* ghist = (int*)base;                    // MAXBK, zeroed
    int* gcur  = ghist + MAXBK;                 // written by bscan
    size_t zbytes = (size_t)MAXBK * 4;
    char* p = base + algn((size_t)2 * MAXBK * 4);
    int*   bbase  = (int*)p;  p += algn((size_t)(MAXBK + 1) * 4);
    int*   rowptr = (int*)p;  p += algn((size_t)(N + 1) * 4);
    float* dinv   = (float*)p; p += algn((size_t)N * 4);
    int2*  pairs  = (int2*)p;  p += algn((size_t)E * 8);
    // region: h (f32, N*32) | vh (bf16, N*16 u32) | vA (bf16) — aliased by tmp
    size_t region = (size_t)N * (128 + 64 + 64);
    if ((size_t)E * 8 > region) region = (size_t)E * 8;
    float*    h   = (float*)p;
    unsigned* vh  = (unsigned*)(p + (size_t)N * 128);
    unsigned* vA  = (unsigned*)(p + (size_t)N * 192);
    int2*     tmp = (int2*)p;  p += algn(region);
    unsigned* vB  = (unsigned*)p; p += algn((size_t)N * 64);
    float* outacc = (float*)p; p += algn((size_t)N * C * 4);
    float* yv     = (float*)p; p += algn((size_t)N * 4);
    (void)ws_size; (void)n_in;

    const int BT = 256;
    const int gNC = ((size_t)N * 32 + BT - 1) / BT;
    const int gN4 = ((size_t)N * 4 + BT - 1) / BT;

    hipMemsetAsync(d_ws, 0, zbytes, stream);

    k_bhist<<<512, BT, 0, stream>>>(col, ghist, E);
    k_bscan<<<1, MAXBK, 0, stream>>>(ghist, bbase, gcur, NBK, E);
    k_part<<<256, 1024, 0, stream>>>(row, col, eattr, gcur, tmp, E);
    k_build<<<NBK, 256, 0, stream>>>(bbase, tmp, rowptr, dinv, pairs, N, E);

    k_inmlp<<<gNC, BT, 0, stream>>>(state, action, Win, bin, dinv, h, vh, N);

    for (int l = 0; l < L; ++l) {
        const float* Wl = Wtaps + (size_t)l * (K + 1) * 32 * 32;
        const float* bl = bgnn + (size_t)l * 32;
        const unsigned* vin = vh;
        for (int k = 1; k <= K; ++k) {
            int first = (k == 1);
            int last  = (k == K);
            int rdout = last && (l == L - 1);
            unsigned* vout = last ? vh : ((k & 1) ? vA : vB);
            k_tap4<<<gN4, BT, 0, stream>>>(rowptr, pairs, (const uv4*)vin, h, dinv,
                                           outacc, (uv4*)vout, h, yv,
                                           Wl, k, bl, Wout, bout,
                                           N, first, last, rdout);
            vin = vout;
        }
    }

    k_segmean<<<B, 256, 0, stream>>>(yv, batch, out, N);
}

// Round 8
// 609.560 us; speedup vs baseline: 1.0449x; 1.0449x over previous
//
#include <hip/hip_runtime.h>

#define LRELU(x) ((x) > 0.f ? (x) : 0.01f * (x))

constexpr int C = 32;
constexpr int BSH = 8;            // 256 dst-nodes per bucket
constexpr int MAXBK = 512;        // max buckets (N <= 131072)

typedef int iv4 __attribute__((ext_vector_type(4)));

// ---- bf16 pack/unpack helpers ----
__device__ __forceinline__ unsigned pk_bf16(float a, float b) {
    unsigned ua = __float_as_uint(a), ub = __float_as_uint(b);
    unsigned ra = (ua + 0x7fffu + ((ua >> 16) & 1u)) >> 16;
    unsigned rb = (ub + 0x7fffu + ((ub >> 16) & 1u)) & 0xffff0000u;
    return ra | rb;
}
__device__ __forceinline__ float lo_bf16(unsigned w) { return __uint_as_float(w << 16); }
__device__ __forceinline__ float hi_bf16(unsigned w) { return __uint_as_float(w & 0xffff0000u); }

// ---- bucket histogram (LDS-privatized) ----
__global__ void k_bhist(const int* __restrict__ col, int* __restrict__ ghist, int E) {
    __shared__ int lh[MAXBK];
    for (int i = threadIdx.x; i < MAXBK; i += blockDim.x) lh[i] = 0;
    __syncthreads();
    int chunk = (E + gridDim.x - 1) / gridDim.x;
    int c0 = blockIdx.x * chunk, c1 = min(E, c0 + chunk);
    for (int e = c0 + threadIdx.x; e < c1; e += blockDim.x)
        atomicAdd(&lh[col[e] >> BSH], 1);
    __syncthreads();
    for (int i = threadIdx.x; i < MAXBK; i += blockDim.x) {
        int v = lh[i];
        if (v) atomicAdd(&ghist[i], v);
    }
}

// ---- exclusive scan of bucket counts -> bbase, gcur ----
__global__ void k_bscan(const int* __restrict__ ghist, int* __restrict__ bbase,
                        int* __restrict__ gcur, int nbk, int E) {
    __shared__ int sm[MAXBK];
    int tid = threadIdx.x;
    int v = (tid < nbk) ? ghist[tid] : 0;
    sm[tid] = v;
    __syncthreads();
    for (int off = 1; off < MAXBK; off <<= 1) {
        int t = (tid >= off) ? sm[tid - off] : 0;
        __syncthreads();
        sm[tid] += t;
        __syncthreads();
    }
    if (tid < nbk) {
        int excl = sm[tid] - v;
        bbase[tid] = excl;
        gcur[tid] = excl;
    }
    if (tid == 0) bbase[nbk] = E;
}

// ---- partition edges into buckets; per-wg claimed contiguous runs ----
// tmp entry: { src | (dstLow8 << 17), ea_bits }
__global__ void k_part(const int* __restrict__ row, const int* __restrict__ col,
                       const float* __restrict__ ea, int* __restrict__ gcur,
                       int2* __restrict__ tmp, int E) {
    __shared__ int lcnt[MAXBK];
    __shared__ int lbase[MAXBK];
    __shared__ int lcur[MAXBK];
    for (int i = threadIdx.x; i < MAXBK; i += blockDim.x) { lcnt[i] = 0; lcur[i] = 0; }
    __syncthreads();
    int chunk = (E + gridDim.x - 1) / gridDim.x;
    int c0 = blockIdx.x * chunk, c1 = min(E, c0 + chunk);
    for (int e = c0 + threadIdx.x; e < c1; e += blockDim.x)
        atomicAdd(&lcnt[col[e] >> BSH], 1);
    __syncthreads();
    for (int b = threadIdx.x; b < MAXBK; b += blockDim.x) {
        int c = lcnt[b];
        lbase[b] = c ? atomicAdd(&gcur[b], c) : 0;
    }
    __syncthreads();
    for (int e = c0 + threadIdx.x; e < c1; e += blockDim.x) {
        int cc = col[e];
        int b = cc >> BSH;
        int r = atomicAdd(&lcur[b], 1);
        tmp[lbase[b] + r] = make_int2(row[e] | ((cc & 255) << 17), __float_as_int(ea[e]));
    }
}

// ---- per-bucket CSR build + within-bucket degree-sorted group permutation ----
__global__ void k_build(const int* __restrict__ bbase, const int2* __restrict__ tmp,
                        int* __restrict__ rowptr, float* __restrict__ dinv,
                        int2* __restrict__ pairs, int* __restrict__ gperm,
                        int N, int E) {
    __shared__ int ncnt[256], noff[256], ncur[256], scn[256];
    __shared__ float ndeg[256];
    __shared__ int dhist[256], dbase[256], dcur[256], dscn[256];
    int tid = threadIdx.x;
    int bg = blockIdx.x;
    int node0 = bg << BSH;
    int s = bbase[bg], e = bbase[bg + 1];
    ncnt[tid] = 0; ncur[tid] = 0; ndeg[tid] = 0.f;
    dhist[tid] = 0; dcur[tid] = 0;
    __syncthreads();
    for (int p = s + tid; p < e; p += 256) {
        int2 u = tmp[p];
        int nl = (u.x >> 17) & 255;
        atomicAdd(&ncnt[nl], 1);
        atomicAdd(&ndeg[nl], __int_as_float(u.y));
    }
    __syncthreads();
    int v = ncnt[tid];
    scn[tid] = v;
    __syncthreads();
    for (int off = 1; off < 256; off <<= 1) {
        int t = (tid >= off) ? scn[tid - off] : 0;
        __syncthreads();
        scn[tid] += t;
        __syncthreads();
    }
    {
        int excl = scn[tid] - v;
        noff[tid] = excl;
        int node = node0 + tid;
        if (node < N) {
            rowptr[node] = s + excl;
            float d = ndeg[tid];
            dinv[node] = d > 0.f ? rsqrtf(fmaxf(d, 1e-12f)) : 0.f;
        }
    }
    if (bg == gridDim.x - 1 && tid == 0) rowptr[N] = E;
    // ---- degree-sorted permutation within bucket ----
    int db = v > 255 ? 255 : v;
    atomicAdd(&dhist[db], 1);
    __syncthreads();
    int dv = dhist[tid];
    dscn[tid] = dv;
    __syncthreads();
    for (int off = 1; off < 256; off <<= 1) {
        int t = (tid >= off) ? dscn[tid - off] : 0;
        __syncthreads();
        dscn[tid] += t;
        __syncthreads();
    }
    dbase[tid] = dscn[tid] - dv;
    __syncthreads();
    {
        int rank = atomicAdd(&dcur[db], 1);
        gperm[(bg << 8) + dbase[db] + rank] = node0 + tid;   // node>=N acts as sentinel
    }
    __syncthreads();
    for (int p = s + tid; p < e; p += 256) {
        int2 u = tmp[p];
        int nl = (u.x >> 17) & 255;
        int r = atomicAdd(&ncur[nl], 1);
        pairs[s + noff[nl] + r] = make_int2(u.x & 0x1FFFF, u.y);
    }
}

// ---- read-in MLP: h = lrelu([state,action]@W_in+b_in); v = bf16(dinv*h) ----
__global__ void k_inmlp(const float* __restrict__ state, const float* __restrict__ action,
                        const float* __restrict__ Win, const float* __restrict__ bin,
                        const float* __restrict__ dinv,
                        float* __restrict__ h, unsigned* __restrict__ v, int N) {
    int t = blockIdx.x * blockDim.x + threadIdx.x;
    int i = t >> 5, c = t & 31;
    if (i >= N) return;
    float acc = bin[c];
#pragma unroll
    for (int d = 0; d < 8; ++d) acc += state[i * 8 + d] * Win[d * 32 + c];
#pragma unroll
    for (int d = 0; d < 2; ++d) acc += action[i * 2 + d] * Win[(8 + d) * 32 + c];
    float hv = LRELU(acc);
    h[i * 32 + c] = hv;
    float vv = dinv[i] * hv;
    float other = __shfl_xor(vv, 1, 32);
    if ((c & 1) == 0) v[(size_t)i * 16 + (c >> 1)] = pk_bf16(vv, other);
}

// acc(4 cols) += z(row, spread over 8 lanes as float4) @ W(32x32), cols 4q..4q+3
__device__ __forceinline__ void mm_acc(float4& acc, float4 zq,
                                       const float* __restrict__ W, int q) {
#pragma unroll
    for (int a = 0; a < 8; ++a) {
        float z0 = __shfl(zq.x, a, 8), z1 = __shfl(zq.y, a, 8);
        float z2 = __shfl(zq.z, a, 8), z3 = __shfl(zq.w, a, 8);
        const float4 w0 = *(const float4*)&W[(4 * a + 0) * 32 + 4 * q];
        const float4 w1 = *(const float4*)&W[(4 * a + 1) * 32 + 4 * q];
        const float4 w2 = *(const float4*)&W[(4 * a + 2) * 32 + 4 * q];
        const float4 w3 = *(const float4*)&W[(4 * a + 3) * 32 + 4 * q];
        acc.x += z0 * w0.x + z1 * w1.x + z2 * w2.x + z3 * w3.x;
        acc.y += z0 * w0.y + z1 * w1.y + z2 * w2.y + z3 * w3.y;
        acc.z += z0 * w0.z + z1 * w1.z + z2 * w2.z + z3 * w3.z;
        acc.w += z0 * w0.w + z1 * w1.w + z2 * w2.w + z3 * w3.w;
    }
}

__device__ __forceinline__ void edge_acc(float4& tv, float w, uint2 x) {
    tv.x += w * lo_bf16(x.x); tv.y += w * hi_bf16(x.x);
    tv.z += w * lo_bf16(x.y); tv.w += w * hi_bf16(x.y);
}

// ---- fused tap; 8 lanes/node; grid-stride over degree-sorted groups;
//      8-edge chunks with next-chunk pair prefetch ----
__global__ __launch_bounds__(256, 4)
void k_tap4(const int* __restrict__ rowptr, const int2* __restrict__ pairs,
            const uint2* __restrict__ vin, const float* __restrict__ hin,
            const float* __restrict__ dinv, const int* __restrict__ gperm,
            float* __restrict__ outacc, uint2* __restrict__ vout,
            float* __restrict__ hout, float* __restrict__ yout,
            const float* __restrict__ Wl, int k, const float* __restrict__ bias,
            const float* __restrict__ Wout, const float* __restrict__ bout,
            int NSLOT, int N, int first, int last, int readout) {
    int t0 = blockIdx.x * blockDim.x + threadIdx.x;
    int q = t0 & 7;
    int stride = (gridDim.x * blockDim.x) >> 3;
    for (int g = t0 >> 3; g < NSLOT; g += stride) {
        int node = gperm[g];
        if (node >= N) continue;
        int s = rowptr[node], e = rowptr[node + 1];
        float4 tv = {0.f, 0.f, 0.f, 0.f};
        int p = s;
        if ((p & 1) && p < e) {             // peel to 16B-aligned pair index
            int2 pr = pairs[p];
            uint2 x = vin[((size_t)(unsigned)pr.x << 3) + q];
            edge_acc(tv, __int_as_float(pr.y), x);
            ++p;
        }
        if (p + 8 <= e) {                   // pipelined 8-edge chunks
            iv4 a0 = *(const iv4*)&pairs[p];
            iv4 a1 = *(const iv4*)&pairs[p + 2];
            iv4 a2 = *(const iv4*)&pairs[p + 4];
            iv4 a3 = *(const iv4*)&pairs[p + 6];
            p += 8;
            while (p + 8 <= e) {
                iv4 b0 = *(const iv4*)&pairs[p];
                iv4 b1 = *(const iv4*)&pairs[p + 2];
                iv4 b2 = *(const iv4*)&pairs[p + 4];
                iv4 b3 = *(const iv4*)&pairs[p + 6];
                uint2 x0 = vin[((size_t)(unsigned)a0[0] << 3) + q];
                uint2 x1 = vin[((size_t)(unsigned)a0[2] << 3) + q];
                uint2 x2 = vin[((size_t)(unsigned)a1[0] << 3) + q];
                uint2 x3 = vin[((size_t)(unsigned)a1[2] << 3) + q];
                uint2 x4 = vin[((size_t)(unsigned)a2[0] << 3) + q];
                uint2 x5 = vin[((size_t)(unsigned)a2[2] << 3) + q];
                uint2 x6 = vin[((size_t)(unsigned)a3[0] << 3) + q];
                uint2 x7 = vin[((size_t)(unsigned)a3[2] << 3) + q];
                edge_acc(tv, __int_as_float(a0[1]), x0);
                edge_acc(tv, __int_as_float(a0[3]), x1);
                edge_acc(tv, __int_as_float(a1[1]), x2);
                edge_acc(tv, __int_as_float(a1[3]), x3);
                edge_acc(tv, __int_as_float(a2[1]), x4);
                edge_acc(tv, __int_as_float(a2[3]), x5);
                edge_acc(tv, __int_as_float(a3[1]), x6);
                edge_acc(tv, __int_as_float(a3[3]), x7);
                a0 = b0; a1 = b1; a2 = b2; a3 = b3;
                p += 8;
            }
            uint2 x0 = vin[((size_t)(unsigned)a0[0] << 3) + q];
            uint2 x1 = vin[((size_t)(unsigned)a0[2] << 3) + q];
            uint2 x2 = vin[((size_t)(unsigned)a1[0] << 3) + q];
            uint2 x3 = vin[((size_t)(unsigned)a1[2] << 3) + q];
            uint2 x4 = vin[((size_t)(unsigned)a2[0] << 3) + q];
            uint2 x5 = vin[((size_t)(unsigned)a2[2] << 3) + q];
            uint2 x6 = vin[((size_t)(unsigned)a3[0] << 3) + q];
            uint2 x7 = vin[((size_t)(unsigned)a3[2] << 3) + q];
            edge_acc(tv, __int_as_float(a0[1]), x0);
            edge_acc(tv, __int_as_float(a0[3]), x1);
            edge_acc(tv, __int_as_float(a1[1]), x2);
            edge_acc(tv, __int_as_float(a1[3]), x3);
            edge_acc(tv, __int_as_float(a2[1]), x4);
            edge_acc(tv, __int_as_float(a2[3]), x5);
            edge_acc(tv, __int_as_float(a3[1]), x6);
            edge_acc(tv, __int_as_float(a3[3]), x7);
        }
        if (p + 4 <= e) {                   // 4-edge step
            iv4 a0 = *(const iv4*)&pairs[p];
            iv4 a1 = *(const iv4*)&pairs[p + 2];
            uint2 x0 = vin[((size_t)(unsigned)a0[0] << 3) + q];
            uint2 x1 = vin[((size_t)(unsigned)a0[2] << 3) + q];
            uint2 x2 = vin[((size_t)(unsigned)a1[0] << 3) + q];
            uint2 x3 = vin[((size_t)(unsigned)a1[2] << 3) + q];
            edge_acc(tv, __int_as_float(a0[1]), x0);
            edge_acc(tv, __int_as_float(a0[3]), x1);
            edge_acc(tv, __int_as_float(a1[1]), x2);
            edge_acc(tv, __int_as_float(a1[3]), x3);
            p += 4;
        }
        for (; p < e; ++p) {                // tail singles
            int2 pr = pairs[p];
            uint2 x = vin[((size_t)(unsigned)pr.x << 3) + q];
            edge_acc(tv, __int_as_float(pr.y), x);
        }
        float di = dinv[node];
        float4 z = {di * tv.x, di * tv.y, di * tv.z, di * tv.w};
        const float* Wk = Wl + (size_t)k * 1024;
        float4 acc;
        if (first) {
            acc = *(const float4*)&bias[4 * q];
            float4 hq = *(const float4*)&hin[(size_t)node * 32 + 4 * q];
            mm_acc(acc, hq, Wl, q);
        } else {
            acc = *(const float4*)&outacc[(size_t)node * 32 + 4 * q];
        }
        mm_acc(acc, z, Wk, q);
        if (!last) {
            *(float4*)&outacc[(size_t)node * 32 + 4 * q] = acc;
            vout[((size_t)node << 3) + q] = make_uint2(pk_bf16(di * z.x, di * z.y),
                                                       pk_bf16(di * z.z, di * z.w));
        } else {
            float4 hv = {LRELU(acc.x), LRELU(acc.y), LRELU(acc.z), LRELU(acc.w)};
            if (!readout) {
                *(float4*)&hout[(size_t)node * 32 + 4 * q] = hv;
                vout[((size_t)node << 3) + q] = make_uint2(pk_bf16(di * hv.x, di * hv.y),
                                                           pk_bf16(di * hv.z, di * hv.w));
            } else {
                const float4 w4 = *(const float4*)&Wout[4 * q];
                float v = hv.x * w4.x + hv.y * w4.y + hv.z * w4.z + hv.w * w4.w;
                v += __shfl_xor(v, 4, 8);
                v += __shfl_xor(v, 2, 8);
                v += __shfl_xor(v, 1, 8);
                if (q == 0) yout[node] = v + bout[0];
            }
        }
    }
}

// ---- segmented mean over sorted batch: one block per graph ----
__global__ void k_segmean(const float* __restrict__ y, const int* __restrict__ batch,
                          float* __restrict__ out, int N) {
    int b = blockIdx.x;
    __shared__ int slo, shi;
    if (threadIdx.x == 0) {
        int lo = 0, hi = N;
        while (lo < hi) { int m = (lo + hi) >> 1; if (batch[m] < b) lo = m + 1; else hi = m; }
        slo = lo;
        hi = N;
        while (lo < hi) { int m = (lo + hi) >> 1; if (batch[m] < b + 1) lo = m + 1; else hi = m; }
        shi = lo;
    }
    __syncthreads();
    int lo = slo, hi = shi;
    float sum = 0.f;
    for (int i = lo + threadIdx.x; i < hi; i += blockDim.x) sum += y[i];
    __shared__ float sm[256];
    sm[threadIdx.x] = sum;
    __syncthreads();
    for (int o = 128; o; o >>= 1) {
        if (threadIdx.x < o) sm[threadIdx.x] += sm[threadIdx.x + o];
        __syncthreads();
    }
    if (threadIdx.x == 0) out[b] = sm[0] / fmaxf((float)(hi - lo), 1.0f);
}

static inline size_t algn(size_t x) { return (x + 255) & ~(size_t)255; }

extern "C" void kernel_launch(void* const* d_in, const int* in_sizes, int n_in,
                              void* d_out, int out_size, void* d_ws, size_t ws_size,
                              hipStream_t stream) {
    const float* state  = (const float*)d_in[0];
    const float* action = (const float*)d_in[1];
    const int*   eidx   = (const int*)d_in[2];
    const float* eattr  = (const float*)d_in[3];
    const int*   batch  = (const int*)d_in[4];
    const float* Win    = (const float*)d_in[5];
    const float* bin    = (const float*)d_in[6];
    const float* Wtaps  = (const float*)d_in[7];
    const float* bgnn   = (const float*)d_in[8];
    const float* Wout   = (const float*)d_in[9];
    const float* bout   = (const float*)d_in[10];
    float* out = (float*)d_out;

    const int N = in_sizes[0] / 8;       // SD=8
    const int E = in_sizes[3];
    const int B = out_size;
    const int K = 4, L = 2;
    const int NBK = (N + 255) >> BSH;
    const int NSLOT = NBK << 8;

    const int* row = eidx;
    const int* col = eidx + E;

    // ---- workspace layout ----
    char* base = (char*)d_ws;
    int* ghist = (int*)base;                    // MAXBK, zeroed
    int* gcur  = ghist + MAXBK;                 // written by bscan
    size_t zbytes = (size_t)MAXBK * 4;
    char* p = base + algn((size_t)2 * MAXBK * 4);
    int*   bbase  = (int*)p;  p += algn((size_t)(MAXBK + 1) * 4);
    int*   rowptr = (int*)p;  p += algn((size_t)(N + 1) * 4);
    float* dinv   = (float*)p; p += algn((size_t)N * 4);
    int*   gperm  = (int*)p;  p += algn((size_t)NSLOT * 4);
    int2*  pairs  = (int2*)p;  p += algn((size_t)E * 8);
    // region: h (f32, N*32) | vh (bf16, N*16 u32) | vA (bf16) — aliased by tmp
    size_t region = (size_t)N * (128 + 64 + 64);
    if ((size_t)E * 8 > region) region = (size_t)E * 8;
    float*    h   = (float*)p;
    unsigned* vh  = (unsigned*)(p + (size_t)N * 128);
    unsigned* vA  = (unsigned*)(p + (size_t)N * 192);
    int2*     tmp = (int2*)p;  p += algn(region);
    unsigned* vB  = (unsigned*)p; p += algn((size_t)N * 64);
    float* outacc = (float*)p; p += algn((size_t)N * C * 4);
    float* yv     = (float*)p; p += algn((size_t)N * 4);
    (void)ws_size; (void)n_in;

    const int BT = 256;
    const int gNC = ((size_t)N * 32 + BT - 1) / BT;

    hipMemsetAsync(d_ws, 0, zbytes, stream);

    k_bhist<<<512, BT, 0, stream>>>(col, ghist, E);
    k_bscan<<<1, MAXBK, 0, stream>>>(ghist, bbase, gcur, NBK, E);
    k_part<<<256, 1024, 0, stream>>>(row, col, eattr, gcur, tmp, E);
    k_build<<<NBK, 256, 0, stream>>>(bbase, tmp, rowptr, dinv, pairs, gperm, N, E);

    k_inmlp<<<gNC, BT, 0, stream>>>(state, action, Win, bin, dinv, h, vh, N);

    for (int l = 0; l < L; ++l) {
        const float* Wl = Wtaps + (size_t)l * (K + 1) * 32 * 32;
        const float* bl = bgnn + (size_t)l * 32;
        const unsigned* vin = vh;
        for (int k = 1; k <= K; ++k) {
            int first = (k == 1);
            int last  = (k == K);
            int rdout = last && (l == L - 1);
            unsigned* vout = last ? vh : ((k & 1) ? vA : vB);
            k_tap4<<<1024, BT, 0, stream>>>(rowptr, pairs, (const uint2*)vin, h, dinv,
                                            gperm, outacc, (uint2*)vout, h, yv,
                                            Wl, k, bl, Wout, bout,
                                            NSLOT, N, first, last, rdout);
            vin = vout;
        }
    }

    k_segmean<<<B, 256, 0, stream>>>(yv, batch, out, N);
}